// Round 15
// baseline (161.664 us; speedup 1.0000x reference)
//
#include <hip/hip_runtime.h>
#include <hip/hip_bf16.h>
#include <math.h>

#define DEV __device__ __forceinline__

typedef __attribute__((ext_vector_type(8))) short short8;
typedef __attribute__((ext_vector_type(8))) unsigned short ushort8v;
typedef __attribute__((ext_vector_type(4))) float f32x4;
typedef __attribute__((ext_vector_type(16))) float f32x16;

DEV unsigned short f2bf(float f) {
  unsigned u = __float_as_uint(f);
  u = u + 0x7fffu + ((u >> 16) & 1u);
  return (unsigned short)(u >> 16);
}

DEV unsigned cvtpk(float a, float b) {
  unsigned r;
  asm("v_cvt_pk_bf16_f32 %0, %1, %2" : "=v"(r) : "v"(a), "v"(b));
  return r;
}

DEV float softplus_f(float x) {
  return (x > 20.f) ? x : log1pf(expf(x));
}

// XOR-swizzled element addressing (16B-chunk granular, stays within the row):
DEV int sw64(int r, int e) { return r * 64 + (e ^ (((r) & 7) << 3)); }
DEV int swKf(int r, int e) { return r * 128 + (e ^ (((r) & 15) << 3)); }  // 16-deep for 32-row reads

// async global->LDS, 16B per lane. LDS dest is wave-uniform base + lane*16 (linear).
#define GL16(gp, lp) __builtin_amdgcn_global_load_lds( \
    (const __attribute__((address_space(1))) unsigned int*)(gp), \
    (__attribute__((address_space(3))) unsigned int*)(lp), 16, 0, 0)

// ---------------------------------------------------------------- fused conversions
__global__ __launch_bounds__(256) void k_convall(
    const float* __restrict__ hs, const float* __restrict__ wq,
    const float* __restrict__ wk, const float* __restrict__ wv,
    const float* __restrict__ wo, ushort4* __restrict__ hsb4,
    ushort4* __restrict__ wcat4, ushort4* __restrict__ wob4) {
  const int i = blockIdx.x * 256 + threadIdx.x;  // < 2097152
  const float* src;
  ushort4* dst;
  int off;
  if (i < 1048576) {
    src = hs; dst = hsb4; off = i;
  } else {
    const int j = i - 1048576;
    const int g = j >> 18;
    off = j & 262143;
    if (g == 0)      { src = wq; dst = wcat4; }
    else if (g == 1) { src = wk; dst = wcat4 + 262144; }
    else if (g == 2) { src = wv; dst = wcat4 + 524288; }
    else             { src = wo; dst = wob4; }
  }
  const float4 v = reinterpret_cast<const float4*>(src)[off];
  ushort4 o;
  o.x = f2bf(v.x); o.y = f2bf(v.y); o.z = f2bf(v.z); o.w = f2bf(v.w);
  dst[off] = o;
}

// ---------------------------------------------------------------- scale + features
__global__ __launch_bounds__(256) void k_prep(
    const float* __restrict__ cos_phi, const float* __restrict__ sin_phi,
    const float* __restrict__ mag, const float* __restrict__ band_logits,
    const float* __restrict__ phase_bias, const float* __restrict__ gamma,
    float* __restrict__ scaleB, unsigned short* __restrict__ feat) {
  const int b = blockIdx.x >> 6;
  const int l0 = ((blockIdx.x >> 2) & 15) << 6;
  const int hq = blockIdx.x & 3;
  const int t = threadIdx.x, lane = t & 63, w = t >> 6;
  __shared__ float cosL[64][65];
  __shared__ float sinL[64][65];
  __shared__ float magL[64][65];
  __shared__ float psum[4][64];
  __shared__ float minv[64];
  __shared__ float bwssL[4][64];
  __shared__ float gposL[4][64];

  {
    const int h = (hq << 2) + w;
    float bl = band_logits[h * 64 + lane];
    float mx = bl;
#pragma unroll
    for (int m = 1; m < 64; m <<= 1) mx = fmaxf(mx, __shfl_xor(mx, m));
    float e = __expf(bl - mx);
    float sm = e;
#pragma unroll
    for (int m = 1; m < 64; m <<= 1) sm += __shfl_xor(sm, m);
    const float ps = softplus_f(phase_bias[h]);
    bwssL[w][lane] = sqrtf(e / sm + 1e-8f) * sqrtf(ps * 0.125f);
    gposL[w][lane] = softplus_f(gamma[h * 64 + lane]);
  }

  const size_t boff = (size_t)b * 65536;  // [B,S,L] stride
  for (int it = 0; it < 16; ++it) {
    const int s = it * 4 + w, l = lane;
    const size_t g = boff + (size_t)s * 1024 + l0 + l;
    cosL[s][l] = cos_phi[g];
    sinL[s][l] = sin_phi[g];
    magL[s][l] = mag[g];
  }
  __syncthreads();
  {
    const int l = t & 63, g = t >> 6;
    float acc = 0.f;
    for (int i = 0; i < 16; ++i) acc += magL[g * 16 + i][l];
    psum[g][l] = acc;
  }
  __syncthreads();
  if (t < 64) {
    float mean = (psum[0][t] + psum[1][t] + psum[2][t] + psum[3][t]) * (1.f / 64.f);
    minv[t] = 1.f / (mean + 1e-8f);
  }
  __syncthreads();
  {
    const int l = lane;
    const float iv = minv[l];
    const int hidx = (hq << 2) + w;
    float acc = 0.f;
    for (int s = 0; s < 64; ++s) acc += magL[s][l] * gposL[w][s];
    const float tnh = tanhf(acc * iv);
    scaleB[(size_t)(((b << 4) + hidx) << 10) + l0 + l] = 1.f + 0.5f * tnh;
  }
  const int l = t >> 2, sq = (t & 3) << 4;
  for (int hh = 0; hh < 4; ++hh) {
    const int h = (hq << 2) + hh;
    unsigned short* fp = feat + ((size_t)(((b << 4) + h) << 10) + l0 + l) * 128;
    unsigned short cb[16], sb[16];
#pragma unroll
    for (int j = 0; j < 16; ++j) {
      const int s = sq + j;
      const float bw = bwssL[hh][s];
      cb[j] = f2bf(bw * cosL[s][l]);
      sb[j] = f2bf(bw * sinL[s][l]);
    }
    *reinterpret_cast<ushort8v*>(fp + sq) = *reinterpret_cast<ushort8v*>(cb);
    *reinterpret_cast<ushort8v*>(fp + sq + 8) = *reinterpret_cast<ushort8v*>(cb + 8);
    *reinterpret_cast<ushort8v*>(fp + 64 + sq) = *reinterpret_cast<ushort8v*>(sb);
    *reinterpret_cast<ushort8v*>(fp + 64 + sq + 8) = *reinterpret_cast<ushort8v*>(sb + 8);
  }
}

// ---------------------------------------------------------------- bf16 MFMA GEMM (B^T)
// 128x128 tile, BK=64 (m97-structure). Bijective XCD swizzle.
// smem union sized 34816B: As[16K] + Bs[16K] for the K-loop; T[128][136] bf16
// (34816B) overlays for the MODE-0 V-tile transpose -> coalesced 16B vT stores.
// <=36.9KB keeps 4 blocks/CU (R14's 64KB allocation halved occupancy -> regressed).
template <int MODE>
__global__ __launch_bounds__(256) void k_gemm(
    const unsigned short* __restrict__ A, const unsigned short* __restrict__ Bt,
    int Ntiles, int K,
    const float* __restrict__ bq, const float* __restrict__ bk,
    const float* __restrict__ bv, const float* __restrict__ scaleB,
    unsigned short* __restrict__ qbuf, unsigned short* __restrict__ kbuf,
    unsigned short* __restrict__ vT,
    const float* __restrict__ bo, const float* __restrict__ resid,
    float* __restrict__ xout) {
  __shared__ __align__(16) char smem[34816];
  short* As = (short*)smem;             // 16384 B
  short* Bs = (short*)(smem + 16384);   // 16384 B
  const int t = threadIdx.x;
  const int lane = t & 63;
  const int w = t >> 6;
  const int cpx = gridDim.x >> 3;
  const int swz = (blockIdx.x & 7) * cpx + (blockIdx.x >> 3);
  const int tm = (swz / Ntiles) << 7;
  const int tn = (swz % Ntiles) << 7;
  const int wR = (w >> 1) << 6;
  const int wC = (w & 1) << 6;
  const int rowS = t >> 3;                 // staging row within 32-row pass
  const int offS = (t & 7) << 3;           // staging k-offset (elements)
  const int sgm = (rowS & 7) << 3;         // inverse stage swizzle (row&7)
  const int ka = (lane >> 4) << 3;
  const int lm = lane & 15;

  const f32x4 vzero = {0.f, 0.f, 0.f, 0.f};
  f32x4 acc[4][4];
#pragma unroll
  for (int i = 0; i < 4; ++i)
#pragma unroll
    for (int j = 0; j < 4; ++j) acc[i][j] = vzero;

  for (int kt = 0; kt < K; kt += 64) {
    __syncthreads();
#pragma unroll
    for (int p = 0; p < 4; ++p) {
      GL16(A + (size_t)(tm + p * 32 + rowS) * K + kt + (offS ^ sgm), smem + p * 4096 + w * 1024);
      GL16(Bt + (size_t)(tn + p * 32 + rowS) * K + kt + (offS ^ sgm), smem + 16384 + p * 4096 + w * 1024);
    }
    __syncthreads();
    short8 af[4][2], bf[4][2];
#pragma unroll
    for (int mt = 0; mt < 4; ++mt) {
      const int r = wR + mt * 16 + lm;
      af[mt][0] = *(const short8*)&As[sw64(r, ka)];
      af[mt][1] = *(const short8*)&As[sw64(r, 32 + ka)];
    }
#pragma unroll
    for (int nt = 0; nt < 4; ++nt) {
      const int r = wC + nt * 16 + lm;
      bf[nt][0] = *(const short8*)&Bs[sw64(r, ka)];
      bf[nt][1] = *(const short8*)&Bs[sw64(r, 32 + ka)];
    }
#pragma unroll
    for (int mt = 0; mt < 4; ++mt)
#pragma unroll
      for (int nt = 0; nt < 4; ++nt) {
        acc[mt][nt] = __builtin_amdgcn_mfma_f32_16x16x32_bf16(af[mt][0], bf[nt][0], acc[mt][nt], 0, 0, 0);
        acc[mt][nt] = __builtin_amdgcn_mfma_f32_16x16x32_bf16(af[mt][1], bf[nt][1], acc[mt][nt], 0, 0, 0);
      }
  }

  if (MODE == 0 && (tn >> 10) == 2) {
    // V-tile: transpose through LDS -> coalesced vT stores along l.
    __syncthreads();  // K-loop LDS reads done everywhere; smem reusable
    unsigned short* T = (unsigned short*)smem;  // [128 hd_local][136 pad] bf16
    const int b0 = tm >> 10;
    const int l0 = tm & 1023;
#pragma unroll
    for (int mt = 0; mt < 4; ++mt) {
#pragma unroll
      for (int r = 0; r < 4; ++r) {
        const int rl = wR + mt * 16 + ((lane >> 4) << 2) + r;  // row_local = l offset
        const int l = l0 + rl;
#pragma unroll
        for (int nt = 0; nt < 4; ++nt) {
          const int cl = wC + nt * 16 + lm;                    // col_local = hd offset
          const int jj = (tn & 1023) + cl;
          const int bh = (b0 << 4) + (jj >> 6);
          const float sc = scaleB[((size_t)bh << 10) + l];
          T[cl * 136 + rl] = f2bf((acc[mt][nt][r] + bv[jj]) * sc);
        }
      }
    }
    __syncthreads();
#pragma unroll
    for (int rep = 0; rep < 8; ++rep) {
      const int c = rep * 256 + t;
      const int hl = c >> 4;            // hd_local 0..127
      const int lc = (c & 15) << 3;     // l chunk start 0..120
      const int jj = (tn & 1023) + hl;
      const int bh = (b0 << 4) + (jj >> 6);
      const int hd = jj & 63;
      const ushort8v vv = *(const ushort8v*)&T[hl * 136 + lc];
      *(ushort8v*)(vT + (size_t)bh * 65536 + (size_t)hd * 1024 + l0 + lc) = vv;
    }
    return;
  }

#pragma unroll
  for (int mt = 0; mt < 4; ++mt) {
#pragma unroll
    for (int r = 0; r < 4; ++r) {
      const int row = tm + wR + mt * 16 + ((lane >> 4) << 2) + r;
#pragma unroll
      for (int nt = 0; nt < 4; ++nt) {
        const int col = tn + wC + nt * 16 + lm;
        float v = acc[mt][nt][r];
        if (MODE == 0) {
          const int b = row >> 10, l = row & 1023;
          const int jj = col & 1023;
          const int h = jj >> 6, hd = jj & 63;
          const int bh = (b << 4) + h;
          const float sc = scaleB[((size_t)bh << 10) + l];
          if ((col >> 10) == 0) {
            qbuf[((size_t)bh * 1024 + l) * 64 + hd] = f2bf((v + bq[jj]) * sc * 0.125f);
          } else {
            kbuf[((size_t)bh * 1024 + l) * 64 + hd] = f2bf((v + bk[jj]) * sc);
          }
        } else {
          xout[(size_t)row * 1024 + col] = v + bo[col] + resid[(size_t)row * 1024 + col];
        }
      }
    }
  }
}

// ---------------------------------------------------------------- flash attention
// R11-EXACT (153.1 us proven): 32x32 swapped-QK, 4 waves x 32 q-rows, QBLK=128,
// KVBLK=64, single-buffer GL16 staging, 2 barriers/round, e-domain softmax,
// defer-max thr=8, Pb pack via cvt_pk, maskS staged.
// LDS: Kq 8K + Kf 16K + Vt 8K + Pb 4x4K + mask 4K = 52KB -> 3 blocks/CU.
__global__ __launch_bounds__(256) void k_attn(
    const unsigned short* __restrict__ qbuf, const unsigned short* __restrict__ kbuf,
    const unsigned short* __restrict__ vT, const unsigned short* __restrict__ feat,
    const float* __restrict__ maskg, unsigned short* __restrict__ ctx) {
  __shared__ __align__(16) short Kq[64 * 64];
  __shared__ __align__(16) short Kf[64 * 128];
  __shared__ __align__(16) short Vt[64 * 64];
  __shared__ __align__(16) short Pb[4][32 * 64];
  __shared__ float maskS[1024];

  const int t = threadIdx.x, lane = t & 63, w = t >> 6;
  const int bh = blockIdx.x & 63;   // same-bh blocks differ by 64 -> same XCD -> L2 reuse
  const int qt = blockIdx.x >> 6;   // 0..7
  const int b = bh >> 4, h = bh & 15;
  const int l31 = lane & 31;
  const int hi = lane >> 5;

  // staging coords (256 threads, 8 GL16/thread)
  const int rA = t >> 3, oA = (t & 7) << 3;     // Kq/Vt: rows rA, rA+32
  const int rF = t >> 4, oF = (t & 15) << 3;    // Kf: rows rF + 16p

  // mask -> LDS once
  reinterpret_cast<float4*>(maskS)[t] =
      reinterpret_cast<const float4*>(maskg + ((size_t)b << 10))[t];

  // Q' B-fragments: 12 K-steps (k = 16*ks + 8*hi + e)
  const size_t qrow = ((size_t)bh << 10) + qt * 128 + w * 32 + l31;
  short8 qf[12];
#pragma unroll
  for (int ks = 0; ks < 4; ++ks)
    qf[ks] = *(const short8*)(qbuf + qrow * 64 + ks * 16 + hi * 8);
#pragma unroll
  for (int ks = 4; ks < 12; ++ks)
    qf[ks] = *(const short8*)(feat + qrow * 128 + (ks - 4) * 16 + hi * 8);

  f32x16 o0, o1;
#pragma unroll
  for (int r = 0; r < 16; ++r) { o0[r] = 0.f; o1[r] = 0.f; }
  float m_i = -INFINITY, l_i = 0.f;

  for (int mt = 0; mt < 16; ++mt) {
    __syncthreads();  // prev round's LDS reads done before restaging
#pragma unroll
    for (int p = 0; p < 2; ++p) {
      const int rr = rA + 32 * p;
      GL16(kbuf + (((size_t)bh << 10) + mt * 64 + rr) * 64 + (oA ^ ((rr & 7) << 3)),
           (char*)Kq + p * 4096 + w * 1024);
      GL16(vT + ((size_t)bh << 16) + (size_t)rr * 1024 + mt * 64 + (oA ^ ((rr & 7) << 3)),
           (char*)Vt + p * 4096 + w * 1024);
    }
#pragma unroll
    for (int p = 0; p < 4; ++p) {
      const int rr = rF + 16 * p;
      GL16(feat + (((size_t)bh << 10) + mt * 64 + rr) * 128 + (oF ^ ((rr & 15) << 3)),
           (char*)Kf + p * 4096 + w * 1024);
    }
    __syncthreads();  // staged data visible

    // S^T = K'(64x192) . Q'^T(192x32) -> two 32(key)x32(q) tiles
    f32x16 s0, s1;
#pragma unroll
    for (int r = 0; r < 16; ++r) { s0[r] = 0.f; s1[r] = 0.f; }
#pragma unroll
    for (int ks = 0; ks < 4; ++ks) {
      const int C = ks * 16 + hi * 8;
      short8 a0 = *(const short8*)&Kq[sw64(l31, C)];
      short8 a1 = *(const short8*)&Kq[sw64(32 + l31, C)];
      s0 = __builtin_amdgcn_mfma_f32_32x32x16_bf16(a0, qf[ks], s0, 0, 0, 0);
      s1 = __builtin_amdgcn_mfma_f32_32x32x16_bf16(a1, qf[ks], s1, 0, 0, 0);
    }
#pragma unroll
    for (int ks = 4; ks < 12; ++ks) {
      const int C = (ks - 4) * 16 + hi * 8;
      short8 a0 = *(const short8*)&Kf[swKf(l31, C)];
      short8 a1 = *(const short8*)&Kf[swKf(32 + l31, C)];
      s0 = __builtin_amdgcn_mfma_f32_32x32x16_bf16(a0, qf[ks], s0, 0, 0, 0);
      s1 = __builtin_amdgcn_mfma_f32_32x32x16_bf16(a1, qf[ks], s1, 0, 0, 0);
    }

    // add mask (indexed by key = row of S^T: key_local = (r&3) + 8*(r>>2) + 4*hi)
#pragma unroll
    for (int j = 0; j < 4; ++j) {
      const float4 mk0 = *(const float4*)&maskS[mt * 64 + j * 8 + hi * 4];
      const float4 mk1 = *(const float4*)&maskS[mt * 64 + 32 + j * 8 + hi * 4];
      s0[4 * j + 0] += mk0.x; s0[4 * j + 1] += mk0.y;
      s0[4 * j + 2] += mk0.z; s0[4 * j + 3] += mk0.w;
      s1[4 * j + 0] += mk1.x; s1[4 * j + 1] += mk1.y;
      s1[4 * j + 2] += mk1.z; s1[4 * j + 3] += mk1.w;
    }

    // per-q max: in-lane tree over 32 values + partner lane (l ^ 32)
    float mx8[8];
#pragma unroll
    for (int i = 0; i < 8; ++i)
      mx8[i] = fmaxf(fmaxf(s0[i], s0[i + 8]), fmaxf(s1[i], s1[i + 8]));
    float pm = fmaxf(fmaxf(fmaxf(mx8[0], mx8[1]), fmaxf(mx8[2], mx8[3])),
                     fmaxf(fmaxf(mx8[4], mx8[5]), fmaxf(mx8[6], mx8[7])));
    pm = fmaxf(pm, __shfl_xor(pm, 32));

    // defer-max (T13)
    float al = 1.f;
    if (__any(pm > m_i + 8.f)) {
      const float mnew = fmaxf(m_i, pm);
      al = __expf(m_i - mnew);
      m_i = mnew;
#pragma unroll
      for (int r = 0; r < 16; ++r) { o0[r] *= al; o1[r] *= al; }
    }

    // exp (in place)
#pragma unroll
    for (int r = 0; r < 16; ++r) {
      s0[r] = __expf(s0[r] - m_i);
      s1[r] = __expf(s1[r] - m_i);
    }

    // per-q sum: in-lane tree + partner
    float sm8[8];
#pragma unroll
    for (int i = 0; i < 8; ++i) sm8[i] = (s0[i] + s0[i + 8]) + (s1[i] + s1[i + 8]);
    float sm = ((sm8[0] + sm8[1]) + (sm8[2] + sm8[3])) +
               ((sm8[4] + sm8[5]) + (sm8[6] + sm8[7]));
    sm += __shfl_xor(sm, 32);
    l_i = l_i * al + sm;

    // pack P -> wave-private LDS [32 q][64 key], swizzled (key-bits 3..5 ^ q&7)
    short* Pw = &Pb[w][0];
#pragma unroll
    for (int j = 0; j < 4; ++j) {
      {
        const int K0 = j * 8 + hi * 4;
        uint2 d;
        d.x = cvtpk(s0[4 * j + 0], s0[4 * j + 1]);
        d.y = cvtpk(s0[4 * j + 2], s0[4 * j + 3]);
        *(uint2*)&Pw[l31 * 64 + (K0 ^ ((l31 & 7) << 3))] = d;
      }
      {
        const int K0 = 32 + j * 8 + hi * 4;
        uint2 d;
        d.x = cvtpk(s1[4 * j + 0], s1[4 * j + 1]);
        d.y = cvtpk(s1[4 * j + 2], s1[4 * j + 3]);
        *(uint2*)&Pw[l31 * 64 + (K0 ^ ((l31 & 7) << 3))] = d;
      }
    }

    // O^T += V^T(64x64) . P^T(64x32): two 32(d)x32(q) tiles, k=64 in 4 steps
#pragma unroll
    for (int ks2 = 0; ks2 < 4; ++ks2) {
      const int C = ks2 * 16 + hi * 8;
      short8 pf = *(const short8*)&Pw[l31 * 64 + (C ^ ((l31 & 7) << 3))];
      short8 v0 = *(const short8*)&Vt[sw64(l31, C)];
      short8 v1 = *(const short8*)&Vt[sw64(32 + l31, C)];
      o0 = __builtin_amdgcn_mfma_f32_32x32x16_bf16(v0, pf, o0, 0, 0, 0);
      o1 = __builtin_amdgcn_mfma_f32_32x32x16_bf16(v1, pf, o1, 0, 0, 0);
    }
  }

  // normalize + transpose through Pb -> coalesced stores
  const float inv = 1.f / l_i;
#pragma unroll
  for (int r = 0; r < 16; ++r) { o0[r] *= inv; o1[r] *= inv; }
  short* Pw = &Pb[w][0];
#pragma unroll
  for (int j = 0; j < 4; ++j) {
    {
      const int D0 = j * 8 + hi * 4;
      uint2 d;
      d.x = cvtpk(o0[4 * j + 0], o0[4 * j + 1]);
      d.y = cvtpk(o0[4 * j + 2], o0[4 * j + 3]);
      *(uint2*)&Pw[l31 * 64 + (D0 ^ ((l31 & 7) << 3))] = d;
    }
    {
      const int D0 = 32 + j * 8 + hi * 4;
      uint2 d;
      d.x = cvtpk(o1[4 * j + 0], o1[4 * j + 1]);
      d.y = cvtpk(o1[4 * j + 2], o1[4 * j + 3]);
      *(uint2*)&Pw[l31 * 64 + (D0 ^ ((l31 & 7) << 3))] = d;
    }
  }
  const int qq = lane >> 3, ch = lane & 7;
#pragma unroll
  for (int p = 0; p < 4; ++p) {
    const int q2 = p * 8 + qq;
    const uint4 vv = *(const uint4*)&Pw[q2 * 64 + ((ch * 8) ^ ((q2 & 7) << 3))];
    const size_t row = ((size_t)b << 10) + qt * 128 + w * 32 + q2;
    *(uint4*)&ctx[row * 1024 + h * 64 + ch * 8] = vv;
  }
}

// ---------------------------------------------------------------- layernorm
__global__ __launch_bounds__(256) void k_ln(const float* __restrict__ x,
                                            const float* __restrict__ lw,
                                            const float* __restrict__ lb,
                                            float* __restrict__ out) {
  const int row = blockIdx.x, t = threadIdx.x, lane = t & 63, w = t >> 6;
  const float4 v = reinterpret_cast<const float4*>(x + (size_t)row * 1024)[t];
  float s = v.x + v.y + v.z + v.w;
  float s2 = v.x * v.x + v.y * v.y + v.z * v.z + v.w * v.w;
#pragma unroll
  for (int m = 1; m < 64; m <<= 1) {
    s += __shfl_xor(s, m);
    s2 += __shfl_xor(s2, m);
  }
  __shared__ float rs[4], rs2[4];
  if (lane == 0) { rs[w] = s; rs2[w] = s2; }
  __syncthreads();
  const float S = rs[0] + rs[1] + rs[2] + rs[3];
  const float S2 = rs2[0] + rs2[1] + rs2[2] + rs2[3];
  const float mu = S * (1.f / 1024.f);
  const float var = fmaxf(S2 * (1.f / 1024.f) - mu * mu, 0.f);
  const float rstd = rsqrtf(var + 1e-12f);
  const float4 wv = reinterpret_cast<const float4*>(lw)[t];
  const float4 bv = reinterpret_cast<const float4*>(lb)[t];
  float4 o;
  o.x = (v.x - mu) * rstd * wv.x + bv.x;
  o.y = (v.y - mu) * rstd * wv.y + bv.y;
  o.z = (v.z - mu) * rstd * wv.z + bv.z;
  o.w = (v.w - mu) * rstd * wv.w + bv.w;
  reinterpret_cast<float4*>(out + (size_t)row * 1024)[t] = o;
}

// ---------------------------------------------------------------- launch
extern "C" void kernel_launch(void* const* d_in, const int* in_sizes, int n_in,
                              void* d_out, int out_size, void* d_ws, size_t ws_size,
                              hipStream_t stream) {
  const float* hs = (const float*)d_in[0];
  const float* mask = (const float*)d_in[1];
  const float* cosp = (const float*)d_in[2];
  const float* sinp = (const float*)d_in[3];
  const float* mag = (const float*)d_in[4];
  const float* Wq = (const float*)d_in[5];
  const float* bq = (const float*)d_in[6];
  const float* Wk = (const float*)d_in[7];
  const float* bk = (const float*)d_in[8];
  const float* Wv = (const float*)d_in[9];
  const float* bv = (const float*)d_in[10];
  const float* Wo = (const float*)d_in[11];
  const float* bo = (const float*)d_in[12];
  const float* bl = (const float*)d_in[13];
  const float* pb = (const float*)d_in[14];
  const float* gm = (const float*)d_in[15];
  const float* lw = (const float*)d_in[16];
  const float* lbv = (const float*)d_in[17];
  float* outp = (float*)d_out;

  char* ws = (char*)d_ws;
  unsigned short* hsb  = (unsigned short*)(ws);              //  8 MB bf16 hidden
  unsigned short* wcat = (unsigned short*)(ws + 8388608);    //  6 MB bf16 [Wq;Wk;Wv]
  unsigned short* wob  = (unsigned short*)(ws + 14680064);   //  2 MB bf16 Wo
  unsigned short* qbuf = (unsigned short*)(ws + 16777216);   //  8 MB [bh][l][64]
  unsigned short* kbuf = (unsigned short*)(ws + 25165824);   //  8 MB [bh][l][64]
  unsigned short* vT   = (unsigned short*)(ws + 33554432);   //  8 MB [bh][hd][l]
  unsigned short* feat = (unsigned short*)(ws + 41943040);   // 16 MB [bh][l][128]
  unsigned short* ctx  = (unsigned short*)(ws + 58720256);   //  8 MB [row][1024]
  float* scaleB = (float*)(ws + 67108864);                   // 256 KB [bh][l]
  float* xbuf   = (float*)(ws + 16777216);                   // 16 MB, aliases q/k (dead by then)

  k_convall<<<8192, 256, 0, stream>>>(hs, Wq, Wk, Wv, Wo, (ushort4*)hsb,
                                      (ushort4*)wcat, (ushort4*)wob);
  k_prep<<<256, 256, 0, stream>>>(cosp, sinp, mag, bl, pb, gm, scaleB, feat);
  k_gemm<0><<<32 * 24, 256, 0, stream>>>(hsb, wcat, 24, 1024, bq, bk, bv, scaleB,
                                         qbuf, kbuf, vT, nullptr, nullptr, nullptr);
  k_attn<<<512, 256, 0, stream>>>(qbuf, kbuf, vT, feat, mask, ctx);
  k_gemm<1><<<32 * 8, 256, 0, stream>>>(ctx, wob, 8, 1024, nullptr, nullptr, nullptr,
                                        nullptr, nullptr, nullptr, nullptr, bo, hs, xbuf);
  k_ln<<<4096, 256, 0, stream>>>(xbuf, lw, lbv, outp);
}

// Round 16
// 152.230 us; speedup vs baseline: 1.0620x; 1.0620x over previous
//
#include <hip/hip_runtime.h>
#include <hip/hip_bf16.h>
#include <math.h>

#define DEV __device__ __forceinline__

typedef __attribute__((ext_vector_type(8))) short short8;
typedef __attribute__((ext_vector_type(8))) unsigned short ushort8v;
typedef __attribute__((ext_vector_type(4))) float f32x4;
typedef __attribute__((ext_vector_type(16))) float f32x16;

DEV unsigned short f2bf(float f) {
  unsigned u = __float_as_uint(f);
  u = u + 0x7fffu + ((u >> 16) & 1u);
  return (unsigned short)(u >> 16);
}

DEV unsigned cvtpk(float a, float b) {
  unsigned r;
  asm("v_cvt_pk_bf16_f32 %0, %1, %2" : "=v"(r) : "v"(a), "v"(b));
  return r;
}

DEV float softplus_f(float x) {
  return (x > 20.f) ? x : log1pf(expf(x));
}

// XOR-swizzled element addressing (16B-chunk granular, stays within the row):
DEV int sw64(int r, int e) { return r * 64 + (e ^ (((r) & 7) << 3)); }
DEV int swKf(int r, int e) { return r * 128 + (e ^ (((r) & 15) << 3)); }  // 16-deep for 32-row reads

// async global->LDS, 16B per lane. LDS dest is wave-uniform base + lane*16 (linear).
#define GL16(gp, lp) __builtin_amdgcn_global_load_lds( \
    (const __attribute__((address_space(1))) unsigned int*)(gp), \
    (__attribute__((address_space(3))) unsigned int*)(lp), 16, 0, 0)

// ---------------------------------------------------------------- fused conversions
__global__ __launch_bounds__(256) void k_convall(
    const float* __restrict__ hs, const float* __restrict__ wq,
    const float* __restrict__ wk, const float* __restrict__ wv,
    const float* __restrict__ wo, ushort4* __restrict__ hsb4,
    ushort4* __restrict__ wcat4, ushort4* __restrict__ wob4) {
  const int i = blockIdx.x * 256 + threadIdx.x;  // < 2097152
  const float* src;
  ushort4* dst;
  int off;
  if (i < 1048576) {
    src = hs; dst = hsb4; off = i;
  } else {
    const int j = i - 1048576;
    const int g = j >> 18;
    off = j & 262143;
    if (g == 0)      { src = wq; dst = wcat4; }
    else if (g == 1) { src = wk; dst = wcat4 + 262144; }
    else if (g == 2) { src = wv; dst = wcat4 + 524288; }
    else             { src = wo; dst = wob4; }
  }
  const float4 v = reinterpret_cast<const float4*>(src)[off];
  ushort4 o;
  o.x = f2bf(v.x); o.y = f2bf(v.y); o.z = f2bf(v.z); o.w = f2bf(v.w);
  dst[off] = o;
}

// ---------------------------------------------------------------- scale + features
__global__ __launch_bounds__(256) void k_prep(
    const float* __restrict__ cos_phi, const float* __restrict__ sin_phi,
    const float* __restrict__ mag, const float* __restrict__ band_logits,
    const float* __restrict__ phase_bias, const float* __restrict__ gamma,
    float* __restrict__ scaleB, unsigned short* __restrict__ feat) {
  const int b = blockIdx.x >> 6;
  const int l0 = ((blockIdx.x >> 2) & 15) << 6;
  const int hq = blockIdx.x & 3;
  const int t = threadIdx.x, lane = t & 63, w = t >> 6;
  __shared__ float cosL[64][65];
  __shared__ float sinL[64][65];
  __shared__ float magL[64][65];
  __shared__ float psum[4][64];
  __shared__ float minv[64];
  __shared__ float bwssL[4][64];
  __shared__ float gposL[4][64];

  {
    const int h = (hq << 2) + w;
    float bl = band_logits[h * 64 + lane];
    float mx = bl;
#pragma unroll
    for (int m = 1; m < 64; m <<= 1) mx = fmaxf(mx, __shfl_xor(mx, m));
    float e = __expf(bl - mx);
    float sm = e;
#pragma unroll
    for (int m = 1; m < 64; m <<= 1) sm += __shfl_xor(sm, m);
    const float ps = softplus_f(phase_bias[h]);
    bwssL[w][lane] = sqrtf(e / sm + 1e-8f) * sqrtf(ps * 0.125f);
    gposL[w][lane] = softplus_f(gamma[h * 64 + lane]);
  }

  const size_t boff = (size_t)b * 65536;  // [B,S,L] stride
  for (int it = 0; it < 16; ++it) {
    const int s = it * 4 + w, l = lane;
    const size_t g = boff + (size_t)s * 1024 + l0 + l;
    cosL[s][l] = cos_phi[g];
    sinL[s][l] = sin_phi[g];
    magL[s][l] = mag[g];
  }
  __syncthreads();
  {
    const int l = t & 63, g = t >> 6;
    float acc = 0.f;
    for (int i = 0; i < 16; ++i) acc += magL[g * 16 + i][l];
    psum[g][l] = acc;
  }
  __syncthreads();
  if (t < 64) {
    float mean = (psum[0][t] + psum[1][t] + psum[2][t] + psum[3][t]) * (1.f / 64.f);
    minv[t] = 1.f / (mean + 1e-8f);
  }
  __syncthreads();
  {
    const int l = lane;
    const float iv = minv[l];
    const int hidx = (hq << 2) + w;
    float acc = 0.f;
    for (int s = 0; s < 64; ++s) acc += magL[s][l] * gposL[w][s];
    const float tnh = tanhf(acc * iv);
    scaleB[(size_t)(((b << 4) + hidx) << 10) + l0 + l] = 1.f + 0.5f * tnh;
  }
  const int l = t >> 2, sq = (t & 3) << 4;
  for (int hh = 0; hh < 4; ++hh) {
    const int h = (hq << 2) + hh;
    unsigned short* fp = feat + ((size_t)(((b << 4) + h) << 10) + l0 + l) * 128;
    unsigned short cb[16], sb[16];
#pragma unroll
    for (int j = 0; j < 16; ++j) {
      const int s = sq + j;
      const float bw = bwssL[hh][s];
      cb[j] = f2bf(bw * cosL[s][l]);
      sb[j] = f2bf(bw * sinL[s][l]);
    }
    *reinterpret_cast<ushort8v*>(fp + sq) = *reinterpret_cast<ushort8v*>(cb);
    *reinterpret_cast<ushort8v*>(fp + sq + 8) = *reinterpret_cast<ushort8v*>(cb + 8);
    *reinterpret_cast<ushort8v*>(fp + 64 + sq) = *reinterpret_cast<ushort8v*>(sb);
    *reinterpret_cast<ushort8v*>(fp + 64 + sq + 8) = *reinterpret_cast<ushort8v*>(sb + 8);
  }
}

// ---------------------------------------------------------------- bf16 MFMA GEMM (B^T)
// 128x128 tile, BK=64 (m97-structure). Bijective XCD swizzle. LDS 32KB. (R11-exact)
template <int MODE>
__global__ __launch_bounds__(256) void k_gemm(
    const unsigned short* __restrict__ A, const unsigned short* __restrict__ Bt,
    int Ntiles, int K,
    const float* __restrict__ bq, const float* __restrict__ bk,
    const float* __restrict__ bv, const float* __restrict__ scaleB,
    unsigned short* __restrict__ qbuf, unsigned short* __restrict__ kbuf,
    unsigned short* __restrict__ vT,
    const float* __restrict__ bo, const float* __restrict__ resid,
    float* __restrict__ xout) {
  __shared__ __align__(16) short As[128 * 64];
  __shared__ __align__(16) short Bs[128 * 64];
  const int t = threadIdx.x;
  const int lane = t & 63;
  const int w = t >> 6;
  const int cpx = gridDim.x >> 3;
  const int swz = (blockIdx.x & 7) * cpx + (blockIdx.x >> 3);
  const int tm = (swz / Ntiles) << 7;
  const int tn = (swz % Ntiles) << 7;
  const int wR = (w >> 1) << 6;
  const int wC = (w & 1) << 6;
  const int rowS = t >> 3;                 // staging row within 32-row pass
  const int offS = (t & 7) << 3;           // staging k-offset (elements)
  const int sgm = (rowS & 7) << 3;         // inverse stage swizzle (row&7)
  const int ka = (lane >> 4) << 3;
  const int lm = lane & 15;

  const f32x4 vzero = {0.f, 0.f, 0.f, 0.f};
  f32x4 acc[4][4];
#pragma unroll
  for (int i = 0; i < 4; ++i)
#pragma unroll
    for (int j = 0; j < 4; ++j) acc[i][j] = vzero;

  for (int kt = 0; kt < K; kt += 64) {
    __syncthreads();
#pragma unroll
    for (int p = 0; p < 4; ++p) {
      GL16(A + (size_t)(tm + p * 32 + rowS) * K + kt + (offS ^ sgm), (char*)As + p * 4096 + w * 1024);
      GL16(Bt + (size_t)(tn + p * 32 + rowS) * K + kt + (offS ^ sgm), (char*)Bs + p * 4096 + w * 1024);
    }
    __syncthreads();
    short8 af[4][2], bf[4][2];
#pragma unroll
    for (int mt = 0; mt < 4; ++mt) {
      const int r = wR + mt * 16 + lm;
      af[mt][0] = *(const short8*)&As[sw64(r, ka)];
      af[mt][1] = *(const short8*)&As[sw64(r, 32 + ka)];
    }
#pragma unroll
    for (int nt = 0; nt < 4; ++nt) {
      const int r = wC + nt * 16 + lm;
      bf[nt][0] = *(const short8*)&Bs[sw64(r, ka)];
      bf[nt][1] = *(const short8*)&Bs[sw64(r, 32 + ka)];
    }
#pragma unroll
    for (int mt = 0; mt < 4; ++mt)
#pragma unroll
      for (int nt = 0; nt < 4; ++nt) {
        acc[mt][nt] = __builtin_amdgcn_mfma_f32_16x16x32_bf16(af[mt][0], bf[nt][0], acc[mt][nt], 0, 0, 0);
        acc[mt][nt] = __builtin_amdgcn_mfma_f32_16x16x32_bf16(af[mt][1], bf[nt][1], acc[mt][nt], 0, 0, 0);
      }
  }

#pragma unroll
  for (int mt = 0; mt < 4; ++mt) {
#pragma unroll
    for (int r = 0; r < 4; ++r) {
      const int row = tm + wR + mt * 16 + ((lane >> 4) << 2) + r;
#pragma unroll
      for (int nt = 0; nt < 4; ++nt) {
        const int col = tn + wC + nt * 16 + lm;
        float v = acc[mt][nt][r];
        if (MODE == 0) {
          const int b = row >> 10, l = row & 1023;
          const int sect = col >> 10, jj = col & 1023;
          const int h = jj >> 6, hd = jj & 63;
          const int bh = (b << 4) + h;
          const float sc = scaleB[((size_t)bh << 10) + l];
          if (sect == 0) {
            qbuf[((size_t)bh * 1024 + l) * 64 + hd] = f2bf((v + bq[jj]) * sc * 0.125f);
          } else if (sect == 1) {
            kbuf[((size_t)bh * 1024 + l) * 64 + hd] = f2bf((v + bk[jj]) * sc);
          } else {
            vT[(size_t)bh * 65536 + (size_t)hd * 1024 + l] = f2bf((v + bv[jj]) * sc);
          }
        } else {
          xout[(size_t)row * 1024 + col] = v + bo[col] + resid[(size_t)row * 1024 + col];
        }
      }
    }
  }
}

// ---------------------------------------------------------------- flash attention
// R11-exact structure (153.1 us proven) + T5 s_setprio around MFMA clusters.
// 32x32 swapped-QK, 4 waves x 32 q-rows, QBLK=128, KVBLK=64, single-buffer GL16
// staging, 2 barriers/round, e-domain softmax, defer-max thr=8, Pb pack via cvt_pk.
// LDS: Kq 8K + Kf 16K + Vt 8K + Pb 4x4K + mask 4K = 52KB -> 3 blocks/CU.
__global__ __launch_bounds__(256) void k_attn(
    const unsigned short* __restrict__ qbuf, const unsigned short* __restrict__ kbuf,
    const unsigned short* __restrict__ vT, const unsigned short* __restrict__ feat,
    const float* __restrict__ maskg, unsigned short* __restrict__ ctx) {
  __shared__ __align__(16) short Kq[64 * 64];
  __shared__ __align__(16) short Kf[64 * 128];
  __shared__ __align__(16) short Vt[64 * 64];
  __shared__ __align__(16) short Pb[4][32 * 64];
  __shared__ float maskS[1024];

  const int t = threadIdx.x, lane = t & 63, w = t >> 6;
  const int bh = blockIdx.x & 63;   // same-bh blocks differ by 64 -> same XCD -> L2 reuse
  const int qt = blockIdx.x >> 6;   // 0..7
  const int b = bh >> 4, h = bh & 15;
  const int l31 = lane & 31;
  const int hi = lane >> 5;

  // staging coords (256 threads, 8 GL16/thread)
  const int rA = t >> 3, oA = (t & 7) << 3;     // Kq/Vt: rows rA, rA+32
  const int rF = t >> 4, oF = (t & 15) << 3;    // Kf: rows rF + 16p

  // mask -> LDS once
  reinterpret_cast<float4*>(maskS)[t] =
      reinterpret_cast<const float4*>(maskg + ((size_t)b << 10))[t];

  // Q' B-fragments: 12 K-steps (k = 16*ks + 8*hi + e)
  const size_t qrow = ((size_t)bh << 10) + qt * 128 + w * 32 + l31;
  short8 qf[12];
#pragma unroll
  for (int ks = 0; ks < 4; ++ks)
    qf[ks] = *(const short8*)(qbuf + qrow * 64 + ks * 16 + hi * 8);
#pragma unroll
  for (int ks = 4; ks < 12; ++ks)
    qf[ks] = *(const short8*)(feat + qrow * 128 + (ks - 4) * 16 + hi * 8);

  f32x16 o0, o1;
#pragma unroll
  for (int r = 0; r < 16; ++r) { o0[r] = 0.f; o1[r] = 0.f; }
  float m_i = -INFINITY, l_i = 0.f;

  for (int mt = 0; mt < 16; ++mt) {
    __syncthreads();  // prev round's LDS reads done before restaging
#pragma unroll
    for (int p = 0; p < 2; ++p) {
      const int rr = rA + 32 * p;
      GL16(kbuf + (((size_t)bh << 10) + mt * 64 + rr) * 64 + (oA ^ ((rr & 7) << 3)),
           (char*)Kq + p * 4096 + w * 1024);
      GL16(vT + ((size_t)bh << 16) + (size_t)rr * 1024 + mt * 64 + (oA ^ ((rr & 7) << 3)),
           (char*)Vt + p * 4096 + w * 1024);
    }
#pragma unroll
    for (int p = 0; p < 4; ++p) {
      const int rr = rF + 16 * p;
      GL16(feat + (((size_t)bh << 10) + mt * 64 + rr) * 128 + (oF ^ ((rr & 15) << 3)),
           (char*)Kf + p * 4096 + w * 1024);
    }
    __syncthreads();  // staged data visible

    // S^T = K'(64x192) . Q'^T(192x32) -> two 32(key)x32(q) tiles
    f32x16 s0, s1;
#pragma unroll
    for (int r = 0; r < 16; ++r) { s0[r] = 0.f; s1[r] = 0.f; }
    __builtin_amdgcn_s_setprio(1);
#pragma unroll
    for (int ks = 0; ks < 4; ++ks) {
      const int C = ks * 16 + hi * 8;
      short8 a0 = *(const short8*)&Kq[sw64(l31, C)];
      short8 a1 = *(const short8*)&Kq[sw64(32 + l31, C)];
      s0 = __builtin_amdgcn_mfma_f32_32x32x16_bf16(a0, qf[ks], s0, 0, 0, 0);
      s1 = __builtin_amdgcn_mfma_f32_32x32x16_bf16(a1, qf[ks], s1, 0, 0, 0);
    }
#pragma unroll
    for (int ks = 4; ks < 12; ++ks) {
      const int C = (ks - 4) * 16 + hi * 8;
      short8 a0 = *(const short8*)&Kf[swKf(l31, C)];
      short8 a1 = *(const short8*)&Kf[swKf(32 + l31, C)];
      s0 = __builtin_amdgcn_mfma_f32_32x32x16_bf16(a0, qf[ks], s0, 0, 0, 0);
      s1 = __builtin_amdgcn_mfma_f32_32x32x16_bf16(a1, qf[ks], s1, 0, 0, 0);
    }
    __builtin_amdgcn_s_setprio(0);

    // add mask (indexed by key = row of S^T: key_local = (r&3) + 8*(r>>2) + 4*hi)
#pragma unroll
    for (int j = 0; j < 4; ++j) {
      const float4 mk0 = *(const float4*)&maskS[mt * 64 + j * 8 + hi * 4];
      const float4 mk1 = *(const float4*)&maskS[mt * 64 + 32 + j * 8 + hi * 4];
      s0[4 * j + 0] += mk0.x; s0[4 * j + 1] += mk0.y;
      s0[4 * j + 2] += mk0.z; s0[4 * j + 3] += mk0.w;
      s1[4 * j + 0] += mk1.x; s1[4 * j + 1] += mk1.y;
      s1[4 * j + 2] += mk1.z; s1[4 * j + 3] += mk1.w;
    }

    // per-q max: in-lane tree over 32 values + partner lane (l ^ 32)
    float mx8[8];
#pragma unroll
    for (int i = 0; i < 8; ++i)
      mx8[i] = fmaxf(fmaxf(s0[i], s0[i + 8]), fmaxf(s1[i], s1[i + 8]));
    float pm = fmaxf(fmaxf(fmaxf(mx8[0], mx8[1]), fmaxf(mx8[2], mx8[3])),
                     fmaxf(fmaxf(mx8[4], mx8[5]), fmaxf(mx8[6], mx8[7])));
    pm = fmaxf(pm, __shfl_xor(pm, 32));

    // defer-max (T13)
    float al = 1.f;
    if (__any(pm > m_i + 8.f)) {
      const float mnew = fmaxf(m_i, pm);
      al = __expf(m_i - mnew);
      m_i = mnew;
#pragma unroll
      for (int r = 0; r < 16; ++r) { o0[r] *= al; o1[r] *= al; }
    }

    // exp (in place)
#pragma unroll
    for (int r = 0; r < 16; ++r) {
      s0[r] = __expf(s0[r] - m_i);
      s1[r] = __expf(s1[r] - m_i);
    }

    // per-q sum: in-lane tree + partner
    float sm8[8];
#pragma unroll
    for (int i = 0; i < 8; ++i) sm8[i] = (s0[i] + s0[i + 8]) + (s1[i] + s1[i + 8]);
    float sm = ((sm8[0] + sm8[1]) + (sm8[2] + sm8[3])) +
               ((sm8[4] + sm8[5]) + (sm8[6] + sm8[7]));
    sm += __shfl_xor(sm, 32);
    l_i = l_i * al + sm;

    // pack P -> wave-private LDS [32 q][64 key], swizzled (key-bits 3..5 ^ q&7)
    short* Pw = &Pb[w][0];
#pragma unroll
    for (int j = 0; j < 4; ++j) {
      {
        const int K0 = j * 8 + hi * 4;
        uint2 d;
        d.x = cvtpk(s0[4 * j + 0], s0[4 * j + 1]);
        d.y = cvtpk(s0[4 * j + 2], s0[4 * j + 3]);
        *(uint2*)&Pw[l31 * 64 + (K0 ^ ((l31 & 7) << 3))] = d;
      }
      {
        const int K0 = 32 + j * 8 + hi * 4;
        uint2 d;
        d.x = cvtpk(s1[4 * j + 0], s1[4 * j + 1]);
        d.y = cvtpk(s1[4 * j + 2], s1[4 * j + 3]);
        *(uint2*)&Pw[l31 * 64 + (K0 ^ ((l31 & 7) << 3))] = d;
      }
    }

    // O^T += V^T(64x64) . P^T(64x32): two 32(d)x32(q) tiles, k=64 in 4 steps
    __builtin_amdgcn_s_setprio(1);
#pragma unroll
    for (int ks2 = 0; ks2 < 4; ++ks2) {
      const int C = ks2 * 16 + hi * 8;
      short8 pf = *(const short8*)&Pw[l31 * 64 + (C ^ ((l31 & 7) << 3))];
      short8 v0 = *(const short8*)&Vt[sw64(l31, C)];
      short8 v1 = *(const short8*)&Vt[sw64(32 + l31, C)];
      o0 = __builtin_amdgcn_mfma_f32_32x32x16_bf16(v0, pf, o0, 0, 0, 0);
      o1 = __builtin_amdgcn_mfma_f32_32x32x16_bf16(v1, pf, o1, 0, 0, 0);
    }
    __builtin_amdgcn_s_setprio(0);
  }

  // normalize + transpose through Pb -> coalesced stores
  const float inv = 1.f / l_i;
#pragma unroll
  for (int r = 0; r < 16; ++r) { o0[r] *= inv; o1[r] *= inv; }
  short* Pw = &Pb[w][0];
#pragma unroll
  for (int j = 0; j < 4; ++j) {
    {
      const int D0 = j * 8 + hi * 4;
      uint2 d;
      d.x = cvtpk(o0[4 * j + 0], o0[4 * j + 1]);
      d.y = cvtpk(o0[4 * j + 2], o0[4 * j + 3]);
      *(uint2*)&Pw[l31 * 64 + (D0 ^ ((l31 & 7) << 3))] = d;
    }
    {
      const int D0 = 32 + j * 8 + hi * 4;
      uint2 d;
      d.x = cvtpk(o1[4 * j + 0], o1[4 * j + 1]);
      d.y = cvtpk(o1[4 * j + 2], o1[4 * j + 3]);
      *(uint2*)&Pw[l31 * 64 + (D0 ^ ((l31 & 7) << 3))] = d;
    }
  }
  const int qq = lane >> 3, ch = lane & 7;
#pragma unroll
  for (int p = 0; p < 4; ++p) {
    const int q2 = p * 8 + qq;
    const uint4 vv = *(const uint4*)&Pw[q2 * 64 + ((ch * 8) ^ ((q2 & 7) << 3))];
    const size_t row = ((size_t)b << 10) + qt * 128 + w * 32 + q2;
    *(uint4*)&ctx[row * 1024 + h * 64 + ch * 8] = vv;
  }
}

// ---------------------------------------------------------------- layernorm
__global__ __launch_bounds__(256) void k_ln(const float* __restrict__ x,
                                            const float* __restrict__ lw,
                                            const float* __restrict__ lb,
                                            float* __restrict__ out) {
  const int row = blockIdx.x, t = threadIdx.x, lane = t & 63, w = t >> 6;
  const float4 v = reinterpret_cast<const float4*>(x + (size_t)row * 1024)[t];
  float s = v.x + v.y + v.z + v.w;
  float s2 = v.x * v.x + v.y * v.y + v.z * v.z + v.w * v.w;
#pragma unroll
  for (int m = 1; m < 64; m <<= 1) {
    s += __shfl_xor(s, m);
    s2 += __shfl_xor(s2, m);
  }
  __shared__ float rs[4], rs2[4];
  if (lane == 0) { rs[w] = s; rs2[w] = s2; }
  __syncthreads();
  const float S = rs[0] + rs[1] + rs[2] + rs[3];
  const float S2 = rs2[0] + rs2[1] + rs2[2] + rs2[3];
  const float mu = S * (1.f / 1024.f);
  const float var = fmaxf(S2 * (1.f / 1024.f) - mu * mu, 0.f);
  const float rstd = rsqrtf(var + 1e-12f);
  const float4 wv = reinterpret_cast<const float4*>(lw)[t];
  const float4 bv = reinterpret_cast<const float4*>(lb)[t];
  float4 o;
  o.x = (v.x - mu) * rstd * wv.x + bv.x;
  o.y = (v.y - mu) * rstd * wv.y + bv.y;
  o.z = (v.z - mu) * rstd * wv.z + bv.z;
  o.w = (v.w - mu) * rstd * wv.w + bv.w;
  reinterpret_cast<float4*>(out + (size_t)row * 1024)[t] = o;
}

// ---------------------------------------------------------------- launch
extern "C" void kernel_launch(void* const* d_in, const int* in_sizes, int n_in,
                              void* d_out, int out_size, void* d_ws, size_t ws_size,
                              hipStream_t stream) {
  const float* hs = (const float*)d_in[0];
  const float* mask = (const float*)d_in[1];
  const float* cosp = (const float*)d_in[2];
  const float* sinp = (const float*)d_in[3];
  const float* mag = (const float*)d_in[4];
  const float* Wq = (const float*)d_in[5];
  const float* bq = (const float*)d_in[6];
  const float* Wk = (const float*)d_in[7];
  const float* bk = (const float*)d_in[8];
  const float* Wv = (const float*)d_in[9];
  const float* bv = (const float*)d_in[10];
  const float* Wo = (const float*)d_in[11];
  const float* bo = (const float*)d_in[12];
  const float* bl = (const float*)d_in[13];
  const float* pb = (const float*)d_in[14];
  const float* gm = (const float*)d_in[15];
  const float* lw = (const float*)d_in[16];
  const float* lbv = (const float*)d_in[17];
  float* outp = (float*)d_out;

  char* ws = (char*)d_ws;
  unsigned short* hsb  = (unsigned short*)(ws);              //  8 MB bf16 hidden
  unsigned short* wcat = (unsigned short*)(ws + 8388608);    //  6 MB bf16 [Wq;Wk;Wv]
  unsigned short* wob  = (unsigned short*)(ws + 14680064);   //  2 MB bf16 Wo
  unsigned short* qbuf = (unsigned short*)(ws + 16777216);   //  8 MB [bh][l][64]
  unsigned short* kbuf = (unsigned short*)(ws + 25165824);   //  8 MB [bh][l][64]
  unsigned short* vT   = (unsigned short*)(ws + 33554432);   //  8 MB [bh][hd][l]
  unsigned short* feat = (unsigned short*)(ws + 41943040);   // 16 MB [bh][l][128]
  unsigned short* ctx  = (unsigned short*)(ws + 58720256);   //  8 MB [row][1024]
  float* scaleB = (float*)(ws + 67108864);                   // 256 KB [bh][l]
  float* xbuf   = (float*)(ws + 16777216);                   // 16 MB, aliases q/k (dead by then)

  k_convall<<<8192, 256, 0, stream>>>(hs, Wq, Wk, Wv, Wo, (ushort4*)hsb,
                                      (ushort4*)wcat, (ushort4*)wob);
  k_prep<<<256, 256, 0, stream>>>(cosp, sinp, mag, bl, pb, gm, scaleB, feat);
  k_gemm<0><<<32 * 24, 256, 0, stream>>>(hsb, wcat, 24, 1024, bq, bk, bv, scaleB,
                                         qbuf, kbuf, vT, nullptr, nullptr, nullptr);
  k_attn<<<512, 256, 0, stream>>>(qbuf, kbuf, vT, feat, mask, ctx);
  k_gemm<1><<<32 * 8, 256, 0, stream>>>(ctx, wob, 8, 1024, nullptr, nullptr, nullptr,
                                        nullptr, nullptr, nullptr, nullptr, bo, hs, xbuf);
  k_ln<<<4096, 256, 0, stream>>>(xbuf, lw, lbv, outp);
}